// Round 9
// baseline (168.879 us; speedup 1.0000x reference)
//
#include <hip/hip_runtime.h>
#include <stdint.h>

// Grossberg shunting ODE, 127 Euler steps, BATCH=32768, N=17.
// R9: 8 lanes/item, CLASS-PURE row split:
//   lane0:{0,1,2} lane1:{3,4} lane2:{5,6} lane3:{7,8}   (needs)
//   lane4:{9,10}  lane5:{11,12}                         (acts)
//   lane6:{13,14} lane7:{15,16}                         (vals)
// W f16-packed register-resident: 54 u32/lane -> total ~100 VGPR, fits the
// 128-reg class => 4096 waves = 4 waves/SIMD (2x latency hiding vs R3) and
// no unified-file AGPR parking. State broadcast: 9 octet ds_swizzle imms.

typedef _Float16 h2 __attribute__((ext_vector_type(2)));
typedef __fp16 h2raw __attribute__((ext_vector_type(2)));
typedef float f2a __attribute__((ext_vector_type(2), aligned(4)));

static constexpr int BATCH = 32768;
static constexpr int NN = 17;
static constexpr int TT = 128;

__device__ __forceinline__ uint32_t pk(float a, float b) {
    h2raw h = __builtin_amdgcn_cvt_pkrtz(a, b);
    return __builtin_bit_cast(uint32_t, h);
}
__device__ __forceinline__ float dot2(uint32_t a, uint32_t b, float c) {
    return __builtin_amdgcn_fdot2(__builtin_bit_cast(h2, a),
                                  __builtin_bit_cast(h2, b), c, false);
}
__device__ __forceinline__ float lo16(uint32_t u) {
    h2 h = __builtin_bit_cast(h2, u); return (float)h.x;
}
__device__ __forceinline__ float hi16(uint32_t u) {
    h2 h = __builtin_bit_cast(h2, u); return (float)h.y;
}
// ds_swizzle BitMode: src_lane = ((lane & and) | or) ^ xor.
// Octet broadcast of octet-lane K: and=0x18, or=K -> (K<<5)|0x18.
template <int K>
__device__ __forceinline__ uint32_t obc(uint32_t v) {
    return (uint32_t)__builtin_amdgcn_ds_swizzle((int)v, (K << 5) | 0x18);
}

__global__ __launch_bounds__(256, 4) void hotco_kernel(
    const float* __restrict__ state0,
    const float* __restrict__ Wpos,
    const float* __restrict__ Wneg,
    const float* __restrict__ feas,
    const float* __restrict__ P,
    const float* __restrict__ t_eval,
    float* __restrict__ out)
{
    const int tid = blockIdx.x * blockDim.x + threadIdx.x;
    const int lq = tid & 7;                  // octet lane
    const int b  = tid >> 3;

    const int sbase = (lq == 0) ? 0 : (2 * lq + 1);   // 0,3,5,7,9,11,13,15
    const int cnt   = (lq == 0) ? 3 : 2;              // rows owned

    // dot2 pair grouping aligned to row ownership:
    // (0,1)(2,-)(3,4)(5,6)(7,8)(9,10)(11,12)(13,14)(15,16)
    constexpr int pA[9] = {0, 2, 3, 5, 7, 9, 11, 13, 15};
    constexpr int pB[9] = {1, -1, 4, 6, 8, 10, 12, 14, 16};

    // ---- W (own rows, both matrices) into registers, packed f16 ----
    uint32_t w[3][9], wn[3][9];
    {
        const float* wpb = Wpos + (size_t)b * (NN * NN);
        const float* wnb = Wneg + (size_t)b * (NN * NN);
#pragma unroll
        for (int t = 0; t < 3; ++t) {
            if (t < cnt) {
                const float* rp = wpb + (sbase + t) * NN;
                const float* rn = wnb + (sbase + t) * NN;
#pragma unroll
                for (int c = 0; c < 9; ++c) {
                    float a2 = (pB[c] < 0) ? 0.f : rp[pB[c]];
                    float b2 = (pB[c] < 0) ? 0.f : rn[pB[c]];
                    w[t][c]  = pk(rp[pA[c]], a2);
                    wn[t][c] = pk(rn[pA[c]], b2);
                }
            } else {
#pragma unroll
                for (int c = 0; c < 9; ++c) { w[t][c] = 0u; wn[t][c] = 0u; }
            }
        }
    }

    // ---- per-lane-class constants ----
    // needs (lq<4):  cE[t]=relu(P_row), cI[t]=relu(-P_row)
    // acts (lq 4,5): gP[s]=P[13+o+s] (gate pert), gF[s]=feas[o+s], o = 0|2
    // vals (lq 6,7): cP[s]=P[13+o+s] (direct drive), o = 0|2
    float cE[3], cI[3], cP[3], gP[2], gF[2];
#pragma unroll
    for (int t = 0; t < 3; ++t) { cE[t] = 0.f; cI[t] = 0.f; cP[t] = 0.f; }
    gP[0] = gP[1] = 0.f; gF[0] = gF[1] = 1.f;
    if (lq < 4) {
#pragma unroll
        for (int t = 0; t < 3; ++t) {
            if (t < cnt) {
                float pv = P[(size_t)b * NN + sbase + t];
                cE[t] = fmaxf(pv, 0.f);
                cI[t] = fmaxf(-pv, 0.f);
            }
        }
    } else if (lq < 6) {
        const int o = (lq == 4) ? 0 : 2;
#pragma unroll
        for (int s = 0; s < 2; ++s) {
            gP[s] = P[(size_t)b * NN + 13 + o + s];
            gF[s] = feas[(size_t)b * 4 + o + s];
        }
    } else {
        const int o = (lq == 6) ? 0 : 2;
#pragma unroll
        for (int s = 0; s < 2; ++s)
            cP[s] = P[(size_t)b * NN + 13 + o + s];
    }

    // ---- initial replicated packed state + own f32 slots ----
    uint32_t s2[9];
    {
        const float* sb_ = state0 + (size_t)b * NN;
        float st[17];
#pragma unroll
        for (int j = 0; j < NN; ++j) st[j] = sb_[j];
        s2[0] = pk(st[0], st[1]);   s2[1] = pk(st[2], 0.f);
        s2[2] = pk(st[3], st[4]);   s2[3] = pk(st[5], st[6]);
        s2[4] = pk(st[7], st[8]);   s2[5] = pk(st[9], st[10]);
        s2[6] = pk(st[11], st[12]); s2[7] = pk(st[13], st[14]);
        s2[8] = pk(st[15], st[16]);
    }
    float sOwn[3];
#pragma unroll
    for (int t = 0; t < 3; ++t)
        sOwn[t] = (t < cnt) ? state0[(size_t)b * NN + sbase + t] : 0.f;

    const float lo = (lq >= 6) ? -1.f : 0.f;
    const float dtv = t_eval[1] - t_eval[0];
    const float k1 = dtv * 1.25f;                 // dt / TAU
    const float C  = -1.0820212806667226f;        // -0.75 * log2(e)

    // ---- write step 0 ----
    {
        float* op = out + (size_t)b * NN + sbase;
        f2a v; v.x = sOwn[0]; v.y = sOwn[1];
        *(f2a*)op = v;
        if (lq == 0) op[2] = sOwn[2];
    }
    float* outp = out + (size_t)BATCH * NN + (size_t)b * NN + sbase;

#pragma unroll 1
    for (int st = 1; st < TT; ++st) {
        // ---- matvec: 3 row-slots x 9 dot2 x {pos,neg}, uniform relu ----
        float E5[3], I5[3];
#pragma unroll
        for (int t = 0; t < 3; ++t) {
            float ae = 0.f, ai = 0.f;
#pragma unroll
            for (int c = 0; c < 9; ++c) {
                ae = dot2(w[t][c], s2[c], ae);
                ai = dot2(wn[t][c], s2[c], ai);
            }
            E5[t] = fmaxf(ae, 0.f);   // relu(g*x) = g*relu(x), g>0
            I5[t] = fmaxf(ai, 0.f);
        }

        // ---- uniform needs adds (constants are 0 on acts/vals lanes) ----
#pragma unroll
        for (int t = 0; t < 3; ++t) { E5[t] += cE[t]; I5[t] += cI[t]; }

        // ---- acts transform: one masked block covering lanes 4 AND 5 ----
        if ((lq & 6) == 4) {
            const uint32_t uv = (lq == 4) ? s2[7] : s2[8];  // val states for gates
            const uint32_t ua = (lq == 4) ? s2[5] : s2[6];  // own acts states
            const float sum_acts = (lo16(s2[5]) + hi16(s2[5]))
                                 + (lo16(s2[6]) + hi16(s2[6]));
#pragma unroll
            for (int s = 0; s < 2; ++s) {
                float v  = ((s == 0) ? lo16(uv) : hi16(uv)) + gP[s];
                float e1 = __builtin_amdgcn_exp2f(C * v);              // e^(-0.75 v)
                float ge = __builtin_amdgcn_rcpf(fmaf(e1, e1, 1.f));   // sigmoid(1.5v)
                float gi = e1 * __builtin_amdgcn_rcpf(1.f + e1);       // sigmoid(-0.75v)
                E5[s] = ge * E5[s] * gF[s];
                float os  = sum_acts - ((s == 0) ? lo16(ua) : hi16(ua));
                float lat = fmaf(-0.9f, __builtin_amdgcn_rcpf(0.3f + os), 3.0f);
                I5[s] = fmaf(gi, I5[s], lat);
            }
        }

        // ---- shunting update + clip (cP = vals direct drive, else 0) ----
#pragma unroll
        for (int t = 0; t < 3; ++t) {
            float s  = sOwn[t];
            float d0 = fmaf(-0.15f, s, cP[t]);
            float d1 = fmaf(1.f - s, E5[t], d0);
            float d2 = fmaf(-(0.1f + s), I5[t], d1);
            float raw = fmaf(k1, d2, s);
            sOwn[t] = fminf(fmaxf(raw, lo), 1.f);
        }

        // ---- pack own rows, octet-broadcast via ds_swizzle imm ----
        uint32_t q0 = pk(sOwn[0], sOwn[1]);
        uint32_t q1 = pk(sOwn[2], 0.f);
        s2[0] = obc<0>(q0); s2[1] = obc<0>(q1);
        s2[2] = obc<1>(q0); s2[3] = obc<2>(q0); s2[4] = obc<3>(q0);
        s2[5] = obc<4>(q0); s2[6] = obc<5>(q0);
        s2[7] = obc<6>(q0); s2[8] = obc<7>(q0);

        // ---- store (dwordx2 + lane0 scalar) ----
        {
            f2a v; v.x = sOwn[0]; v.y = sOwn[1];
            *(f2a*)outp = v;
            if (lq == 0) outp[2] = sOwn[2];
        }
        outp += (size_t)BATCH * NN;
    }
}

extern "C" void kernel_launch(void* const* d_in, const int* in_sizes, int n_in,
                              void* d_out, int out_size, void* d_ws, size_t ws_size,
                              hipStream_t stream) {
    const float* state0 = (const float*)d_in[0];
    const float* Wpos   = (const float*)d_in[1];
    const float* Wneg   = (const float*)d_in[2];
    const float* feasv  = (const float*)d_in[3];
    const float* P      = (const float*)d_in[4];
    const float* t_eval = (const float*)d_in[5];
    float* out = (float*)d_out;

    dim3 grid(BATCH * 8 / 256), block(256);
    hipLaunchKernelGGL(hotco_kernel, grid, block, 0, stream,
                       state0, Wpos, Wneg, feasv, P, t_eval, out);
}

// Round 10
// 148.258 us; speedup vs baseline: 1.1391x; 1.1391x over previous
//
#include <hip/hip_runtime.h>
#include <stdint.h>

// Grossberg shunting ODE, 127 Euler steps, BATCH=32768, N=17.
// R8 base (4 lanes/item, W f16-packed register-resident, dot2 matvec,
// ds_swizzle imm quad-broadcast) +
// R10: packed-f32 (v_pk_*) relu/add/update/clamp on slot pairs, unroll 2.

typedef _Float16 h2 __attribute__((ext_vector_type(2)));
typedef __fp16 h2raw __attribute__((ext_vector_type(2)));
typedef float f4a __attribute__((ext_vector_type(4), aligned(4)));
typedef float f2 __attribute__((ext_vector_type(2)));

static constexpr int BATCH = 32768;
static constexpr int NN = 17;
static constexpr int TT = 128;

__device__ __forceinline__ uint32_t pk(float a, float b) {
    h2raw h = __builtin_amdgcn_cvt_pkrtz(a, b);
    return __builtin_bit_cast(uint32_t, h);
}
__device__ __forceinline__ float dot2(uint32_t a, uint32_t b, float c) {
    return __builtin_amdgcn_fdot2(__builtin_bit_cast(h2, a),
                                  __builtin_bit_cast(h2, b), c, false);
}
__device__ __forceinline__ float lo16(uint32_t u) {
    h2 h = __builtin_bit_cast(h2, u); return (float)h.x;
}
__device__ __forceinline__ float hi16(uint32_t u) {
    h2 h = __builtin_bit_cast(h2, u); return (float)h.y;
}
// ds_swizzle BitMode: src_lane = ((lane & and) | or) ^ xor.
// Quad broadcast of quad-lane K: and=0x1C, or=K -> (K<<5)|0x1C.
template <int K>
__device__ __forceinline__ uint32_t qswz(uint32_t v) {
    return (uint32_t)__builtin_amdgcn_ds_swizzle((int)v, (K << 5) | 0x1C);
}

__global__ __launch_bounds__(256, 2) void hotco_kernel(
    const float* __restrict__ state0,
    const float* __restrict__ Wpos,
    const float* __restrict__ Wneg,
    const float* __restrict__ feas,
    const float* __restrict__ P,
    const float* __restrict__ t_eval,
    float* __restrict__ out)
{
    const int tid = blockIdx.x * blockDim.x + threadIdx.x;
    const int lane4 = tid & 3;
    const int b = tid >> 2;
    if (b >= BATCH) return;

    // lane0: rows 0-4 (needs), lane1: 5-8 (needs), lane2: 9-12 (acts), lane3: 13-16 (vals)
    const int base = (lane4 == 0) ? 0 : (4 * lane4 + 1);
    const int nrows = (lane4 == 0) ? 5 : 4;

    // pair grouping: (0,1)(2,3)(4,-)(5,6)(7,8)(9,10)(11,12)(13,14)(15,16)
    constexpr int pA[9] = {0, 2, 4, 5, 7, 9, 11, 13, 15};
    constexpr int pB[9] = {1, 3, -1, 6, 8, 10, 12, 14, 16};

    // ---- W into registers, packed f16 pairs (90 u32 per lane) ----
    uint32_t w[5][9], wn[5][9];
    {
        const float* wpb = Wpos + (size_t)b * (NN * NN);
        const float* wnb = Wneg + (size_t)b * (NN * NN);
#pragma unroll
        for (int t = 0; t < 5; ++t) {
            if (t < nrows) {
                const float* rp = wpb + (base + t) * NN;
                const float* rn = wnb + (base + t) * NN;
#pragma unroll
                for (int c = 0; c < 9; ++c) {
                    float a2 = (pB[c] < 0) ? 0.f : rp[pB[c]];
                    float b2 = (pB[c] < 0) ? 0.f : rn[pB[c]];
                    w[t][c]  = pk(rp[pA[c]], a2);
                    wn[t][c] = pk(rn[pA[c]], b2);
                }
            } else {
#pragma unroll
                for (int c = 0; c < 9; ++c) { w[t][c] = 0u; wn[t][c] = 0u; }
            }
        }
    }

    // ---- per-lane-class constants, slot-pair layout ----
    // needs lanes (0,1): cA = relu(P), cB = relu(-P)
    // acts lane  (2)   : cA = feasibility, cB = gate perturbation P[13+t]
    // vals lane  (3)   : pdv = P[13+t] direct drive
    f2 cA01 = {0.f, 0.f}, cA23 = {0.f, 0.f};
    f2 cB01 = {0.f, 0.f}, cB23 = {0.f, 0.f};
    f2 pdv01 = {0.f, 0.f}, pdv23 = {0.f, 0.f};
    float cA4 = 0.f, cB4 = 0.f;
    if (lane4 < 2) {
        float t0 = P[(size_t)b * NN + base + 0];
        float t1 = P[(size_t)b * NN + base + 1];
        float t2 = P[(size_t)b * NN + base + 2];
        float t3 = P[(size_t)b * NN + base + 3];
        cA01 = f2{fmaxf(t0, 0.f), fmaxf(t1, 0.f)};
        cA23 = f2{fmaxf(t2, 0.f), fmaxf(t3, 0.f)};
        cB01 = f2{fmaxf(-t0, 0.f), fmaxf(-t1, 0.f)};
        cB23 = f2{fmaxf(-t2, 0.f), fmaxf(-t3, 0.f)};
        if (nrows == 5) {
            float t4 = P[(size_t)b * NN + base + 4];
            cA4 = fmaxf(t4, 0.f);
            cB4 = fmaxf(-t4, 0.f);
        }
    } else if (lane4 == 2) {
        cA01 = f2{feas[(size_t)b * 4 + 0], feas[(size_t)b * 4 + 1]};
        cA23 = f2{feas[(size_t)b * 4 + 2], feas[(size_t)b * 4 + 3]};
        cB01 = f2{P[(size_t)b * NN + 13], P[(size_t)b * NN + 14]};
        cB23 = f2{P[(size_t)b * NN + 15], P[(size_t)b * NN + 16]};
    } else {
        pdv01 = f2{P[(size_t)b * NN + 13], P[(size_t)b * NN + 14]};
        pdv23 = f2{P[(size_t)b * NN + 15], P[(size_t)b * NN + 16]};
    }

    // ---- initial replicated packed state + own slots (pair layout) ----
    uint32_t s2[9];
    {
        const float* sb = state0 + (size_t)b * NN;
        float st[17];
#pragma unroll
        for (int j = 0; j < NN; ++j) st[j] = sb[j];
        s2[0] = pk(st[0], st[1]);   s2[1] = pk(st[2], st[3]);
        s2[2] = pk(st[4], 0.f);     s2[3] = pk(st[5], st[6]);
        s2[4] = pk(st[7], st[8]);   s2[5] = pk(st[9], st[10]);
        s2[6] = pk(st[11], st[12]); s2[7] = pk(st[13], st[14]);
        s2[8] = pk(st[15], st[16]);
    }
    f2 s01, s23; float s4;
    {
        const float* sb = state0 + (size_t)b * NN + base;
        s01 = f2{sb[0], sb[1]};
        s23 = f2{sb[2], sb[3]};
        s4 = (nrows == 5) ? sb[4] : 0.f;
    }

    const float lof = (lane4 == 3) ? -1.f : 0.f;
    const f2 lov = {lof, lof};
    const f2 onev = {1.f, 1.f};
    const f2 c01v = {0.1f, 0.1f};
    const f2 zerov = {0.f, 0.f};
    const float dtv = t_eval[1] - t_eval[0];
    const float k1 = dtv * 1.25f;                 // dt / TAU
    const f2 k1v = {k1, k1};
    const float C  = -1.0820212806667226f;        // -0.75 * log2(e)

    // ---- write step 0 ----
    {
        float* op = out + (size_t)b * NN + base;
        f4a v0; v0.x = s01.x; v0.y = s01.y; v0.z = s23.x; v0.w = s23.y;
        *(f4a*)op = v0;
        if (nrows == 5) op[4] = s4;
    }
    float* outp = out + (size_t)BATCH * NN + (size_t)b * NN + base;

#pragma unroll 2
    for (int st = 1; st < TT; ++st) {
        // ---- matvec: 2 x (5 rows x 9 dot2) ----
        float ae[5], ai[5];
#pragma unroll
        for (int t = 0; t < 5; ++t) {
            float e = 0.f, i = 0.f;
#pragma unroll
            for (int c = 0; c < 9; ++c) {
                e = dot2(w[t][c], s2[c], e);
                i = dot2(wn[t][c], s2[c], i);
            }
            ae[t] = e; ai[t] = i;
        }

        // ---- packed relu (relu(g*x) = g*relu(x), g>0) ----
        f2 e01 = __builtin_elementwise_max(f2{ae[0], ae[1]}, zerov);
        f2 e23 = __builtin_elementwise_max(f2{ae[2], ae[3]}, zerov);
        f2 i01 = __builtin_elementwise_max(f2{ai[0], ai[1]}, zerov);
        f2 i23 = __builtin_elementwise_max(f2{ai[2], ai[3]}, zerov);
        float e4 = fmaxf(ae[4], 0.f);
        float i4 = fmaxf(ai[4], 0.f);

        // ---- class transform ----
        if (lane4 == 2) {
            const float sum_acts = (s01.x + s01.y) + (s23.x + s23.y);
            float ee[4] = {e01.x, e01.y, e23.x, e23.y};
            float ii[4] = {i01.x, i01.y, i23.x, i23.y};
            const float so[4] = {s01.x, s01.y, s23.x, s23.y};
            const float v13[4] = {lo16(s2[7]), hi16(s2[7]), lo16(s2[8]), hi16(s2[8])};
            const float gp[4] = {cB01.x, cB01.y, cB23.x, cB23.y};
            const float gf[4] = {cA01.x, cA01.y, cA23.x, cA23.y};
#pragma unroll
            for (int t = 0; t < 4; ++t) {
                float v  = v13[t] + gp[t];
                float x1 = __builtin_amdgcn_exp2f(C * v);              // e^(-0.75 v)
                float ge = __builtin_amdgcn_rcpf(fmaf(x1, x1, 1.f));   // sigmoid(1.5v)
                float gi = x1 * __builtin_amdgcn_rcpf(1.f + x1);       // sigmoid(-0.75v)
                ee[t] = ge * ee[t] * gf[t];
                float os  = sum_acts - so[t];
                float lat = fmaf(-0.9f, __builtin_amdgcn_rcpf(0.3f + os), 3.0f);
                ii[t] = fmaf(gi, ii[t], lat);
            }
            e01 = f2{ee[0], ee[1]}; e23 = f2{ee[2], ee[3]};
            i01 = f2{ii[0], ii[1]}; i23 = f2{ii[2], ii[3]};
            e4 = 0.f; i4 = 0.f;
        } else {
            e01 += cA01; e23 += cA23; e4 += cA4;
            i01 += cB01; i23 += cB23; i4 += cB4;
        }

        // ---- packed shunting update + clip ----
        // d = (1-s)*E - (0.1+s)*I - 0.15*s + pdv ; s' = clip(s + k1*d)
        {
            f2 d0 = __builtin_elementwise_fma(f2{-0.15f, -0.15f}, s01, pdv01);
            f2 d1 = __builtin_elementwise_fma(onev - s01, e01, d0);
            f2 d2 = __builtin_elementwise_fma(zerov - (c01v + s01), i01, d1);
            f2 raw = __builtin_elementwise_fma(k1v, d2, s01);
            s01 = __builtin_elementwise_min(__builtin_elementwise_max(raw, lov), onev);
        }
        {
            f2 d0 = __builtin_elementwise_fma(f2{-0.15f, -0.15f}, s23, pdv23);
            f2 d1 = __builtin_elementwise_fma(onev - s23, e23, d0);
            f2 d2 = __builtin_elementwise_fma(zerov - (c01v + s23), i23, d1);
            f2 raw = __builtin_elementwise_fma(k1v, d2, s23);
            s23 = __builtin_elementwise_min(__builtin_elementwise_max(raw, lov), onev);
        }
        {
            float d0 = -0.15f * s4;
            float d1 = fmaf(1.f - s4, e4, d0);
            float d2 = fmaf(-(0.1f + s4), i4, d1);
            float raw = fmaf(k1, d2, s4);
            s4 = fminf(fmaxf(raw, lof), 1.f);
        }

        // ---- pack own block, quad-broadcast via ds_swizzle imm ----
        uint32_t p0 = pk(s01.x, s01.y);
        uint32_t p1 = pk(s23.x, s23.y);
        uint32_t p2 = pk(s4, 0.f);
        s2[0] = qswz<0>(p0); s2[1] = qswz<0>(p1); s2[2] = qswz<0>(p2);
        s2[3] = qswz<1>(p0); s2[4] = qswz<1>(p1);
        s2[5] = qswz<2>(p0); s2[6] = qswz<2>(p1);
        s2[7] = qswz<3>(p0); s2[8] = qswz<3>(p1);

        // ---- store (float4 + lane0 scalar) ----
        {
            f4a v0; v0.x = s01.x; v0.y = s01.y; v0.z = s23.x; v0.w = s23.y;
            *(f4a*)outp = v0;
            if (nrows == 5) outp[4] = s4;
        }
        outp += (size_t)BATCH * NN;
    }
}

extern "C" void kernel_launch(void* const* d_in, const int* in_sizes, int n_in,
                              void* d_out, int out_size, void* d_ws, size_t ws_size,
                              hipStream_t stream) {
    const float* state0 = (const float*)d_in[0];
    const float* Wpos   = (const float*)d_in[1];
    const float* Wneg   = (const float*)d_in[2];
    const float* feasv  = (const float*)d_in[3];
    const float* P      = (const float*)d_in[4];
    const float* t_eval = (const float*)d_in[5];
    float* out = (float*)d_out;

    dim3 grid(BATCH * 4 / 256), block(256);
    hipLaunchKernelGGL(hotco_kernel, grid, block, 0, stream,
                       state0, Wpos, Wneg, feasv, P, t_eval, out);
}